// Round 8
// baseline (157.874 us; speedup 1.0000x reference)
//
#include <hip/hip_runtime.h>
#include <hip/hip_cooperative_groups.h>

namespace cg = cooperative_groups;

#define NCLS 1000
#define NDF  256
#define BB   512
#define O_LD 1024

#define BM 32
#define BN 64
#define BK 32
#define NCHUNK (NDF / BK)   // 8
#define NBLK 512

typedef __attribute__((ext_vector_type(8))) short short8;
typedef __attribute__((ext_vector_type(4))) float floatx4;

static __device__ __forceinline__ unsigned short f2bf(float f) {
    unsigned int u = __float_as_uint(f);
    u += 0x7FFFu + ((u >> 16) & 1u);   // RNE
    return (unsigned short)(u >> 16);
}

// GEMM pipe (byte-identical math to the R5/R7 passing kernel).
template <bool FULL>
static __device__ __forceinline__ void run_pipe(
    const float* __restrict__ ap, const float* __restrict__ bp, bool bok,
    unsigned short (&Ah)[2][BM][BK], unsigned short (&Bh)[2][BN][BK],
    int arow, int ak, int brow, int bk,
    int r16, int c32, int lr, int lk,
    floatx4& acc0, floatx4& acc1)
{
    float4 va = *(const float4*)ap;
    float4 vb0, vb1;
    if (FULL || bok) { vb0 = *(const float4*)bp; vb1 = *(const float4*)(bp + 4); }
    else { vb0 = make_float4(0.f, 0.f, 0.f, 0.f); vb1 = vb0; }

    *(ushort4*)&Ah[0][arow][ak] =
        make_ushort4(f2bf(va.x), f2bf(va.y), f2bf(va.z), f2bf(va.w));
    *(ushort4*)&Bh[0][brow][bk] =
        make_ushort4(f2bf(vb0.x), f2bf(vb0.y), f2bf(vb0.z), f2bf(vb0.w));
    *(ushort4*)&Bh[0][brow][bk + 4] =
        make_ushort4(f2bf(vb1.x), f2bf(vb1.y), f2bf(vb1.z), f2bf(vb1.w));
    __syncthreads();

    for (int c = 0; c < NCHUNK; ++c) {
        int cur = c & 1;
        float4 na, nb0, nb1;
        if (c + 1 < NCHUNK) {
            int k0 = (c + 1) * BK;
            na = *(const float4*)(ap + k0);
            if (FULL || bok) {
                nb0 = *(const float4*)(bp + k0);
                nb1 = *(const float4*)(bp + k0 + 4);
            } else {
                nb0 = make_float4(0.f, 0.f, 0.f, 0.f); nb1 = nb0;
            }
        }
        short8 a  = *(const short8*)&Ah[cur][r16 + lr][lk];
        short8 b0 = *(const short8*)&Bh[cur][c32 + lr][lk];
        short8 b1 = *(const short8*)&Bh[cur][c32 + 16 + lr][lk];
        acc0 = __builtin_amdgcn_mfma_f32_16x16x32_bf16(a, b0, acc0, 0, 0, 0);
        acc1 = __builtin_amdgcn_mfma_f32_16x16x32_bf16(a, b1, acc1, 0, 0, 0);
        if (c + 1 < NCHUNK) {
            int nxt = cur ^ 1;
            *(ushort4*)&Ah[nxt][arow][ak] =
                make_ushort4(f2bf(na.x), f2bf(na.y), f2bf(na.z), f2bf(na.w));
            *(ushort4*)&Bh[nxt][brow][bk] =
                make_ushort4(f2bf(nb0.x), f2bf(nb0.y), f2bf(nb0.z), f2bf(nb0.w));
            *(ushort4*)&Bh[nxt][brow][bk + 4] =
                make_ushort4(f2bf(nb1.x), f2bf(nb1.y), f2bf(nb1.z), f2bf(nb1.w));
            __syncthreads();
        }
    }
}

// Single cooperative kernel: phase 1 = MFMA GEMM (blocks 0..255), grid sync,
// phase 2 = ballot-scan combine (block i = output row i).
__global__ __launch_bounds__(256) void fused_coop(
    const float* __restrict__ df, const int* __restrict__ gt,
    const float* __restrict__ fc, float* __restrict__ O,
    float* __restrict__ out)
{
    __shared__ unsigned short Ah[2][BM][BK];
    __shared__ unsigned short Bh[2][BN][BK];
    __shared__ unsigned long long masks[8];

    int tid = threadIdx.x;
    int b = blockIdx.x;

    // ---------------- phase 1: G = df . fc^T ----------------
    if (b < 256) {
        int m0 = (b >> 4) * BM;
        int j0 = (b & 15) * BN;

        int arow = tid >> 3, ak = (tid & 7) * 4;
        int brow = tid >> 2, bk = (tid & 3) * 8;
        const float* ap = df + (size_t)(m0 + arow) * NDF + ak;
        const float* bp = fc + (size_t)(j0 + brow) * NDF + bk;
        bool bok = (j0 + brow) < NCLS;

        int lane = tid & 63, w = tid >> 6;
        int r16 = (w & 1) * 16, c32 = (w >> 1) * 32;
        int lr = lane & 15, lk = (lane >> 4) * 8;

        floatx4 acc0 = {0.f, 0.f, 0.f, 0.f}, acc1 = {0.f, 0.f, 0.f, 0.f};

        if (j0 + BN <= NCLS) {
            run_pipe<true>(ap, bp, bok, Ah, Bh, arow, ak, brow, bk,
                           r16, c32, lr, lk, acc0, acc1);
        } else {
            run_pipe<false>(ap, bp, bok, Ah, Bh, arow, ak, brow, bk,
                            r16, c32, lr, lk, acc0, acc1);
        }

        // C/D layout: col = lane&15, row = (lane>>4)*4 + reg  [m89-verified]
        int orow = m0 + r16 + (lane >> 4) * 4;
        int ocol = j0 + c32 + lr;
#pragma unroll
        for (int r = 0; r < 4; ++r) {
            O[(size_t)(orow + r) * O_LD + ocol]      = acc0[r];
            O[(size_t)(orow + r) * O_LD + ocol + 16] = acc1[r];
        }
    }

    __threadfence();            // device-scope release of O (cross-XCD, G16)
    cg::this_grid().sync();
    __threadfence();            // acquire side

    // ---------------- phase 2: combine, row i = b ----------------
    int i = b;
    int t = gt[i];                        // broadcast
    int g0 = gt[tid], g1 = gt[tid + 256]; // coalesced
    unsigned long long bal0 = __ballot(g0 == t);
    unsigned long long bal1 = __ballot(g1 == t);
    int wv = tid >> 6;
    if ((tid & 63) == 0) { masks[wv] = bal0; masks[wv + 4] = bal1; }
    __syncthreads();

    int j = tid * 4;
    if (j >= NCLS) return;                // no barriers below

    // n = #occurrences of class t at positions <= i (always >= 1)
    int n = 0;
#pragma unroll
    for (int wi = 0; wi < 8; ++wi) {
        int d = i - wi * 64;
        unsigned long long mk = masks[wi];
        if (d >= 64)      n += __popcll(mk);
        else if (d >= 0)  n += __popcll(mk & ((2ULL << d) - 1ULL));
    }

    const float* Grow = O + (size_t)i * O_LD;
    float4 gv = *(const float4*)&Grow[j];
    float gtv = Grow[t];
    float gx = gv.x - gtv, gy = gv.y - gtv, gz = gv.z - gtv, gw = gv.w - gtv;
    float qx = 0.f, qy = 0.f, qz = 0.f, qw = 0.f;

    if (n >= 2) {
        float invn = 1.f / (float)n;
        float Sx = 0.f, Sy = 0.f, Sz = 0.f, Sw = 0.f, St = 0.f;
        int m = 0;
        for (int wi = 0; wi < 8 && m < n; ++wi) {
            unsigned long long mk = masks[wi];
            while (mk && m < n) {
                int bpos = __builtin_ctzll(mk);
                mk &= mk - 1ULL;
                int s = wi * 64 + bpos;
                float4 Gsj = *(const float4*)&O[(size_t)s * O_LD + j];
                float Gst = O[(size_t)s * O_LD + t];
                ++m;
                Sx += Gsj.x; Sy += Gsj.y; Sz += Gsj.z; Sw += Gsj.w; St += Gst;
                if (m >= 2) {
                    float inv_m = 1.f / (float)m;
                    float ht = Gst - St * inv_m;
                    float hx = (Gsj.x - Sx * inv_m) - ht;
                    float hy = (Gsj.y - Sy * inv_m) - ht;
                    float hz = (Gsj.z - Sz * inv_m) - ht;
                    float hw = (Gsj.w - Sw * inv_m) - ht;
                    float coef = (float)(m - 1) * inv_m * invn;
                    qx += coef * hx * hx;
                    qy += coef * hy * hy;
                    qz += coef * hz * hz;
                    qw += coef * hw * hw;
                }
            }
        }
    }
    // NCLS % 4 == 0 -> float4 store exact; 1000*4B row pitch keeps 16B align
    *(float4*)&out[(size_t)i * NCLS + j] =
        make_float4(gx + 0.05f * qx, gy + 0.05f * qy,
                    gz + 0.05f * qz, gw + 0.05f * qw);   // 0.5*ALP = 0.05
}

extern "C" void kernel_launch(void* const* d_in, const int* in_sizes, int n_in,
                              void* d_out, int out_size, void* d_ws, size_t ws_size,
                              hipStream_t stream) {
    const float* df = (const float*)d_in[0];
    const int*   gt = (const int*)d_in[1];
    const float* fc = (const float*)d_in[2];
    float* out = (float*)d_out;
    float* O = (float*)d_ws;   // 512*1024*4 = 2 MB workspace

    void* args[] = { (void*)&df, (void*)&gt, (void*)&fc, (void*)&O, (void*)&out };
    hipLaunchCooperativeKernel((const void*)fused_coop, dim3(NBLK), dim3(256),
                               args, 0, stream);
}

// Round 9
// 140.107 us; speedup vs baseline: 1.1268x; 1.1268x over previous
//
#include <hip/hip_runtime.h>

#define NCLS 1000
#define NDF  256
#define BB   512
#define O_LD 1024

#define BM 32
#define BN 64
#define BK 32
#define NCHUNK (NDF / BK)   // 8
#define NBLK 512

typedef __attribute__((ext_vector_type(8))) short short8;
typedef __attribute__((ext_vector_type(4))) float floatx4;

static __device__ __forceinline__ unsigned short f2bf(float f) {
    unsigned int u = __float_as_uint(f);
    u += 0x7FFFu + ((u >> 16) & 1u);   // RNE
    return (unsigned short)(u >> 16);
}

// GEMM pipe (byte-identical math to the R5/R7 passing kernel).
template <bool FULL>
static __device__ __forceinline__ void run_pipe(
    const float* __restrict__ ap, const float* __restrict__ bp, bool bok,
    unsigned short (&Ah)[2][BM][BK], unsigned short (&Bh)[2][BN][BK],
    int arow, int ak, int brow, int bk,
    int r16, int c32, int lr, int lk,
    floatx4& acc0, floatx4& acc1)
{
    float4 va = *(const float4*)ap;
    float4 vb0, vb1;
    if (FULL || bok) { vb0 = *(const float4*)bp; vb1 = *(const float4*)(bp + 4); }
    else { vb0 = make_float4(0.f, 0.f, 0.f, 0.f); vb1 = vb0; }

    *(ushort4*)&Ah[0][arow][ak] =
        make_ushort4(f2bf(va.x), f2bf(va.y), f2bf(va.z), f2bf(va.w));
    *(ushort4*)&Bh[0][brow][bk] =
        make_ushort4(f2bf(vb0.x), f2bf(vb0.y), f2bf(vb0.z), f2bf(vb0.w));
    *(ushort4*)&Bh[0][brow][bk + 4] =
        make_ushort4(f2bf(vb1.x), f2bf(vb1.y), f2bf(vb1.z), f2bf(vb1.w));
    __syncthreads();

    for (int c = 0; c < NCHUNK; ++c) {
        int cur = c & 1;
        float4 na, nb0, nb1;
        if (c + 1 < NCHUNK) {
            int k0 = (c + 1) * BK;
            na = *(const float4*)(ap + k0);
            if (FULL || bok) {
                nb0 = *(const float4*)(bp + k0);
                nb1 = *(const float4*)(bp + k0 + 4);
            } else {
                nb0 = make_float4(0.f, 0.f, 0.f, 0.f); nb1 = nb0;
            }
        }
        short8 a  = *(const short8*)&Ah[cur][r16 + lr][lk];
        short8 b0 = *(const short8*)&Bh[cur][c32 + lr][lk];
        short8 b1 = *(const short8*)&Bh[cur][c32 + 16 + lr][lk];
        acc0 = __builtin_amdgcn_mfma_f32_16x16x32_bf16(a, b0, acc0, 0, 0, 0);
        acc1 = __builtin_amdgcn_mfma_f32_16x16x32_bf16(a, b1, acc1, 0, 0, 0);
        if (c + 1 < NCHUNK) {
            int nxt = cur ^ 1;
            *(ushort4*)&Ah[nxt][arow][ak] =
                make_ushort4(f2bf(na.x), f2bf(na.y), f2bf(na.z), f2bf(na.w));
            *(ushort4*)&Bh[nxt][brow][bk] =
                make_ushort4(f2bf(nb0.x), f2bf(nb0.y), f2bf(nb0.z), f2bf(nb0.w));
            *(ushort4*)&Bh[nxt][brow][bk + 4] =
                make_ushort4(f2bf(nb1.x), f2bf(nb1.y), f2bf(nb1.z), f2bf(nb1.w));
            __syncthreads();
        }
    }
}

// Single kernel: phase 1 = MFMA GEMM (blocks 0..255), hand-rolled grid barrier
// (all 512 blocks provably co-resident: 2048/8192 waves, 2 blocks/CU), phase 2 =
// ballot-scan combine (block i = output row i). Counter zeroed by a memset node.
__global__ __launch_bounds__(256) void fused_manual(
    const float* __restrict__ df, const int* __restrict__ gt,
    const float* __restrict__ fc, float* __restrict__ O,
    float* __restrict__ out, int* __restrict__ cnt)
{
    __shared__ unsigned short Ah[2][BM][BK];
    __shared__ unsigned short Bh[2][BN][BK];
    __shared__ unsigned long long masks[8];

    int tid = threadIdx.x;
    int b = blockIdx.x;

    // ---------------- phase 1: G = df . fc^T ----------------
    if (b < 256) {
        int m0 = (b >> 4) * BM;
        int j0 = (b & 15) * BN;

        int arow = tid >> 3, ak = (tid & 7) * 4;
        int brow = tid >> 2, bk = (tid & 3) * 8;
        const float* ap = df + (size_t)(m0 + arow) * NDF + ak;
        const float* bp = fc + (size_t)(j0 + brow) * NDF + bk;
        bool bok = (j0 + brow) < NCLS;

        int lane = tid & 63, w = tid >> 6;
        int r16 = (w & 1) * 16, c32 = (w >> 1) * 32;
        int lr = lane & 15, lk = (lane >> 4) * 8;

        floatx4 acc0 = {0.f, 0.f, 0.f, 0.f}, acc1 = {0.f, 0.f, 0.f, 0.f};

        if (j0 + BN <= NCLS) {
            run_pipe<true>(ap, bp, bok, Ah, Bh, arow, ak, brow, bk,
                           r16, c32, lr, lk, acc0, acc1);
        } else {
            run_pipe<false>(ap, bp, bok, Ah, Bh, arow, ak, brow, bk,
                            r16, c32, lr, lk, acc0, acc1);
        }

        // C/D layout: col = lane&15, row = (lane>>4)*4 + reg  [m89-verified]
        int orow = m0 + r16 + (lane >> 4) * 4;
        int ocol = j0 + c32 + lr;
#pragma unroll
        for (int r = 0; r < 4; ++r) {
            O[(size_t)(orow + r) * O_LD + ocol]      = acc0[r];
            O[(size_t)(orow + r) * O_LD + ocol + 16] = acc1[r];
        }
    }

    // ---------------- hand-rolled grid barrier (1 round) ----------------
    __threadfence();   // agent-scope release of this block's O tile
    if (tid == 0) {
        __hip_atomic_fetch_add(cnt, 1, __ATOMIC_RELEASE, __HIP_MEMORY_SCOPE_AGENT);
        while (__hip_atomic_load(cnt, __ATOMIC_ACQUIRE, __HIP_MEMORY_SCOPE_AGENT)
               < NBLK) {
            __builtin_amdgcn_s_sleep(4);
        }
    }
    __syncthreads();
    __threadfence();   // acquire side: make all O tiles visible to this block

    // ---------------- phase 2: combine, row i = b (R8-verified) ----------------
    int i = b;
    int t = gt[i];                        // broadcast
    int g0 = gt[tid], g1 = gt[tid + 256]; // coalesced
    unsigned long long bal0 = __ballot(g0 == t);
    unsigned long long bal1 = __ballot(g1 == t);
    int wv = tid >> 6;
    if ((tid & 63) == 0) { masks[wv] = bal0; masks[wv + 4] = bal1; }
    __syncthreads();

    int j = tid * 4;
    if (j >= NCLS) return;                // no barriers below

    // n = #occurrences of class t at positions <= i (always >= 1)
    int n = 0;
#pragma unroll
    for (int wi = 0; wi < 8; ++wi) {
        int d = i - wi * 64;
        unsigned long long mk = masks[wi];
        if (d >= 64)      n += __popcll(mk);
        else if (d >= 0)  n += __popcll(mk & ((2ULL << d) - 1ULL));
    }

    const float* Grow = O + (size_t)i * O_LD;
    float4 gv = *(const float4*)&Grow[j];
    float gtv = Grow[t];
    float gx = gv.x - gtv, gy = gv.y - gtv, gz = gv.z - gtv, gw = gv.w - gtv;
    float qx = 0.f, qy = 0.f, qz = 0.f, qw = 0.f;

    if (n >= 2) {
        float invn = 1.f / (float)n;
        float Sx = 0.f, Sy = 0.f, Sz = 0.f, Sw = 0.f, St = 0.f;
        int m = 0;
        for (int wi = 0; wi < 8 && m < n; ++wi) {
            unsigned long long mk = masks[wi];
            while (mk && m < n) {
                int bpos = __builtin_ctzll(mk);
                mk &= mk - 1ULL;
                int s = wi * 64 + bpos;
                float4 Gsj = *(const float4*)&O[(size_t)s * O_LD + j];
                float Gst = O[(size_t)s * O_LD + t];
                ++m;
                Sx += Gsj.x; Sy += Gsj.y; Sz += Gsj.z; Sw += Gsj.w; St += Gst;
                if (m >= 2) {
                    float inv_m = 1.f / (float)m;
                    float ht = Gst - St * inv_m;
                    float hx = (Gsj.x - Sx * inv_m) - ht;
                    float hy = (Gsj.y - Sy * inv_m) - ht;
                    float hz = (Gsj.z - Sz * inv_m) - ht;
                    float hw = (Gsj.w - Sw * inv_m) - ht;
                    float coef = (float)(m - 1) * inv_m * invn;
                    qx += coef * hx * hx;
                    qy += coef * hy * hy;
                    qz += coef * hz * hz;
                    qw += coef * hw * hw;
                }
            }
        }
    }
    // NCLS % 4 == 0 -> float4 store exact; 1000*4B row pitch keeps 16B align
    *(float4*)&out[(size_t)i * NCLS + j] =
        make_float4(gx + 0.05f * qx, gy + 0.05f * qy,
                    gz + 0.05f * qz, gw + 0.05f * qw);   // 0.5*ALP = 0.05
}

extern "C" void kernel_launch(void* const* d_in, const int* in_sizes, int n_in,
                              void* d_out, int out_size, void* d_ws, size_t ws_size,
                              hipStream_t stream) {
    const float* df = (const float*)d_in[0];
    const int*   gt = (const int*)d_in[1];
    const float* fc = (const float*)d_in[2];
    float* out = (float*)d_out;

    char* ws = (char*)d_ws;
    int*   cnt = (int*)ws;               // 4 B barrier counter (slot 4096)
    float* O   = (float*)(ws + 4096);    // 512*1024*4 = 2 MB

    hipMemsetAsync(cnt, 0, sizeof(int), stream);   // graph-capture-safe

    void* args[] = { (void*)&df, (void*)&gt, (void*)&fc,
                     (void*)&O, (void*)&out, (void*)&cnt };
    hipLaunchKernel((const void*)fused_manual, dim3(NBLK), dim3(256),
                    args, 0, stream);
}

// Round 10
// 24.532 us; speedup vs baseline: 6.4354x; 5.7112x over previous
//
#include <hip/hip_runtime.h>

#define NCLS 1000
#define NDF  256
#define BB   512

typedef __attribute__((ext_vector_type(8))) short short8;
typedef __attribute__((ext_vector_type(4))) float floatx4;

static __device__ __forceinline__ unsigned short f2bf(float f) {
    unsigned int u = __float_as_uint(f);
    u += 0x7FFFu + ((u >> 16) & 1u);   // RNE
    return (unsigned short)(u >> 16);
}
static __device__ __forceinline__ short8 cvt8(float4 a, float4 b) {
    short8 r;
    r[0] = (short)f2bf(a.x); r[1] = (short)f2bf(a.y);
    r[2] = (short)f2bf(a.z); r[3] = (short)f2bf(a.w);
    r[4] = (short)f2bf(b.x); r[5] = (short)f2bf(b.y);
    r[6] = (short)f2bf(b.z); r[7] = (short)f2bf(b.w);
    return r;
}

// One dispatch, no grid sync. Block (ct, rw) owns out rows m0..m0+31, cols
// j0..j0+63. Cross-row coupling (occurrence rows s < m0 of the window's
// classes) is recomputed locally: gather -> rank-sort -> MFMA chunks, with
// incremental combine state walked in ascending step order (R7-verified math).
__global__ __launch_bounds__(256) void fused_one(
    const float* __restrict__ df, const int* __restrict__ gt,
    const float* __restrict__ fc, float* __restrict__ out)
{
    __shared__ int            s_gt[BB];
    __shared__ unsigned char  s_flag[1024];
    __shared__ short          s_xlist[BB];
    __shared__ short          s_xsort[BB];
    __shared__ int            s_E;
    __shared__ unsigned short Bh[64][264];   // fc col-tile, bf16, pad 8
    __shared__ float          Gown[32][66];  // own G tile
    __shared__ float          Gx[32][66];    // extras chunk G
    __shared__ float          s_v[32];       // v[own row] = df.fc[class]
    __shared__ float          s_vx[32];      // v[extras chunk row]
    __shared__ float          s_part[32][8];
    __shared__ int            s_ncnt[32][8];

    int tid = threadIdx.x;
    int j0 = blockIdx.x * 64;
    int m0 = blockIdx.y * 32;

    s_gt[tid]       = gt[tid];
    s_gt[tid + 256] = gt[tid + 256];
    ((int*)s_flag)[tid] = 0;
    if (tid == 0) s_E = 0;
    __syncthreads();
    if (tid < 32) s_flag[s_gt[m0 + tid]] = 1;   // races write same value
    __syncthreads();

    // gather predecessors (k < m0) of window classes
    for (int k = tid; k < m0; k += 256)
        if (s_flag[s_gt[k]]) { int p = atomicAdd(&s_E, 1); s_xlist[p] = (short)k; }
    __syncthreads();
    int E  = s_E;
    int NC = (E + 31) >> 5;
    // rank-sort ascending (values distinct); pad tail for safe staging reads
    for (int z = tid; z < E; z += 256) {
        int val = (int)s_xlist[z], rank = 0;
        for (int z2 = 0; z2 < E; ++z2) rank += ((int)s_xlist[z2] < val) ? 1 : 0;
        s_xsort[rank] = (short)val;
    }
    for (int z = E + tid; z < NC * 32; z += 256) s_xsort[z] = 0;

    // stage fc col-tile -> Bh bf16 (clamp OOB cols to row NCLS-1; never stored)
    {
        int row = tid >> 2, kb = (tid & 3) * 64;
        int fr = j0 + row; if (fr > NCLS - 1) fr = NCLS - 1;
        const float* fp = fc + (size_t)fr * NDF + kb;
#pragma unroll
        for (int u = 0; u < 64; u += 8) {
            float4 x = *(const float4*)(fp + u);
            float4 y = *(const float4*)(fp + u + 4);
            *(short8*)&Bh[row][kb + u] = cvt8(x, y);
        }
    }

    int r = tid >> 3, c8 = tid & 7;      // combine mapping: 32 rows x 8 colgroups
    int i_row = m0 + r;
    int t_cls = s_gt[i_row];

    // n[i] = #occurrences of class at positions <= i  (8-way split scan)
    {
        int lim = i_row + 1;
        int seg = (lim + 7) >> 3;
        int k0 = c8 * seg;
        int k1 = k0 + seg; if (k1 > lim) k1 = lim;
        int cnt = 0;
        for (int k = k0; k < k1; ++k) cnt += (s_gt[k] == t_cls) ? 1 : 0;
        s_ncnt[r][c8] = cnt;
    }
    // own v partial: df[i] . fc[t] over k-slice
    {
        const float* dp = df + (size_t)i_row * NDF + c8 * 32;
        const float* fp = fc + (size_t)t_cls * NDF + c8 * 32;
        float a = 0.f;
#pragma unroll
        for (int u = 0; u < 32; u += 4) {
            float4 x = *(const float4*)(dp + u);
            float4 y = *(const float4*)(fp + u);
            a += x.x * y.x + x.y * y.y + x.z * y.z + x.w * y.w;
        }
        s_part[r][c8] = a;
    }
    __syncthreads();                      // B1: Bh, ncnt, vpart, xsort ready

    int n_i = 0;
#pragma unroll
    for (int u = 0; u < 8; ++u) n_i += s_ncnt[r][u];
    float invn = 1.f / (float)n_i;
    if (tid < 32) {
        float v = 0.f;
#pragma unroll
        for (int u = 0; u < 8; ++u) v += s_part[tid][u];
        s_v[tid] = v;
    }

    // own-tile MFMA (fragment layout verified R5/m89)
    int lane = tid & 63, w = tid >> 6;
    int lr = lane & 15, lk8 = (lane >> 4) * 8;
    int cf = w * 16;
    {
        floatx4 accA = {0.f, 0.f, 0.f, 0.f}, accB = accA;
        const float* a0p = df + (size_t)(m0 + lr) * NDF + lk8;
        const float* a1p = df + (size_t)(m0 + 16 + lr) * NDF + lk8;
#pragma unroll
        for (int ks = 0; ks < 8; ++ks) {
            int kb = ks * 32;
            short8 bfrag = *(short8*)&Bh[cf + lr][kb + lk8];
            short8 a0 = cvt8(*(const float4*)(a0p + kb), *(const float4*)(a0p + kb + 4));
            short8 a1 = cvt8(*(const float4*)(a1p + kb), *(const float4*)(a1p + kb + 4));
            accA = __builtin_amdgcn_mfma_f32_16x16x32_bf16(a0, bfrag, accA, 0, 0, 0);
            accB = __builtin_amdgcn_mfma_f32_16x16x32_bf16(a1, bfrag, accB, 0, 0, 0);
        }
        int rb = (lane >> 4) * 4;
#pragma unroll
        for (int g = 0; g < 4; ++g) {
            Gown[rb + g][cf + lr]      = accA[g];
            Gown[16 + rb + g][cf + lr] = accB[g];
        }
    }

    // incremental combine state (statically indexed)
    float S[8] = {0.f,0.f,0.f,0.f,0.f,0.f,0.f,0.f};
    float q[8] = {0.f,0.f,0.f,0.f,0.f,0.f,0.f,0.f};
    float St = 0.f;
    int mcnt = 0;

    // extras chunks, ascending step order (all rows < m0)
    for (int c = 0; c < NC; ++c) {
        __syncthreads();                  // B2: prev Gx/vx consumed; vpart free
        // chunk v partials
        {
            int slot = c * 32 + r;
            int srow = (int)s_xsort[slot];
            int st = s_gt[srow];
            const float* dp = df + (size_t)srow * NDF + c8 * 32;
            const float* fp = fc + (size_t)st * NDF + c8 * 32;
            float a = 0.f;
#pragma unroll
            for (int u = 0; u < 32; u += 4) {
                float4 x = *(const float4*)(dp + u);
                float4 y = *(const float4*)(fp + u);
                a += x.x * y.x + x.y * y.y + x.z * y.z + x.w * y.w;
            }
            s_part[r][c8] = a;
        }
        // chunk MFMA (gathered rows)
        {
            int sb = c * 32;
            int sr0 = (int)s_xsort[sb + lr];
            int sr1 = (int)s_xsort[sb + 16 + lr];
            const float* e0p = df + (size_t)sr0 * NDF + lk8;
            const float* e1p = df + (size_t)sr1 * NDF + lk8;
            floatx4 accA = {0.f, 0.f, 0.f, 0.f}, accB = accA;
#pragma unroll
            for (int ks = 0; ks < 8; ++ks) {
                int kb = ks * 32;
                short8 bfrag = *(short8*)&Bh[cf + lr][kb + lk8];
                short8 a0 = cvt8(*(const float4*)(e0p + kb), *(const float4*)(e0p + kb + 4));
                short8 a1 = cvt8(*(const float4*)(e1p + kb), *(const float4*)(e1p + kb + 4));
                accA = __builtin_amdgcn_mfma_f32_16x16x32_bf16(a0, bfrag, accA, 0, 0, 0);
                accB = __builtin_amdgcn_mfma_f32_16x16x32_bf16(a1, bfrag, accB, 0, 0, 0);
            }
            int rb = (lane >> 4) * 4;
#pragma unroll
            for (int g = 0; g < 4; ++g) {
                Gx[rb + g][cf + lr]      = accA[g];
                Gx[16 + rb + g][cf + lr] = accB[g];
            }
        }
        __syncthreads();                  // B3: Gx, vpart ready
        if (tid < 32) {
            float v = 0.f;
#pragma unroll
            for (int u = 0; u < 8; ++u) v += s_part[tid][u];
            s_vx[tid] = v;
        }
        __syncthreads();                  // B4: vx ready
        // combine update over this chunk
        int lim = E - c * 32; if (lim > 32) lim = 32;
        for (int z = 0; z < lim; ++z) {
            int srow = (int)s_xsort[c * 32 + z];
            if (s_gt[srow] == t_cls) {
                ++mcnt;
                float vz = s_vx[z];
                St += vz;
                float inv_m = 1.f / (float)mcnt;
                float Gz[8];
#pragma unroll
                for (int u = 0; u < 8; ++u) { Gz[u] = Gx[z][c8 * 8 + u]; S[u] += Gz[u]; }
                if (mcnt >= 2) {
                    float ht = vz - St * inv_m;
                    float coef = (float)(mcnt - 1) * inv_m * invn;
#pragma unroll
                    for (int u = 0; u < 8; ++u) {
                        float h = (Gz[u] - S[u] * inv_m) - ht;
                        q[u] += coef * h * h;
                    }
                }
            }
        }
    }

    __syncthreads();                      // B5: Gown/s_v visible (covers NC==0)

    // own-window occurrences (steps m0..i), ascending
    for (int r2 = 0; r2 <= r; ++r2) {
        int srow = m0 + r2;
        if (s_gt[srow] == t_cls) {
            ++mcnt;
            float vz = s_v[r2];
            St += vz;
            float inv_m = 1.f / (float)mcnt;
            float Gz[8];
#pragma unroll
            for (int u = 0; u < 8; ++u) { Gz[u] = Gown[r2][c8 * 8 + u]; S[u] += Gz[u]; }
            if (mcnt >= 2) {
                float ht = vz - St * inv_m;
                float coef = (float)(mcnt - 1) * inv_m * invn;
#pragma unroll
                for (int u = 0; u < 8; ++u) {
                    float h = (Gz[u] - S[u] * inv_m) - ht;
                    q[u] += coef * h * h;
                }
            }
        }
    }

    // out[i][j] = (G[i][j] - v[i]) + 0.05 * q    (0.5*ALP = 0.05)
    int j = j0 + c8 * 8;
    if (j < NCLS) {                       // NCLS%8==0 -> exact group guard
        float res[8];
#pragma unroll
        for (int u = 0; u < 8; ++u)
            res[u] = (Gown[r][c8 * 8 + u] - s_v[r]) + 0.05f * q[u];
        float* op = out + (size_t)i_row * NCLS + j;
        *(float4*)op       = make_float4(res[0], res[1], res[2], res[3]);
        *(float4*)(op + 4) = make_float4(res[4], res[5], res[6], res[7]);
    }
}

extern "C" void kernel_launch(void* const* d_in, const int* in_sizes, int n_in,
                              void* d_out, int out_size, void* d_ws, size_t ws_size,
                              hipStream_t stream) {
    const float* df = (const float*)d_in[0];
    const int*   gt = (const int*)d_in[1];
    const float* fc = (const float*)d_in[2];
    float* out = (float*)d_out;
    (void)d_ws; (void)ws_size;

    fused_one<<<dim3(16, 16), 256, 0, stream>>>(df, gt, fc, out);
}

// Round 11
// 21.489 us; speedup vs baseline: 7.3468x; 1.1416x over previous
//
#include <hip/hip_runtime.h>

#define NCLS 1000
#define NDF  256
#define BB   512
#define WROWS 16
#define WCOLS 64
#define EMAX  96

typedef __attribute__((ext_vector_type(8))) short short8;
typedef __attribute__((ext_vector_type(4))) float floatx4;

static __device__ __forceinline__ unsigned short f2bf(float f) {
    unsigned int u = __float_as_uint(f);
    u += 0x7FFFu + ((u >> 16) & 1u);   // RNE
    return (unsigned short)(u >> 16);
}
static __device__ __forceinline__ short8 cvt8(float4 a, float4 b) {
    short8 r;
    r[0] = (short)f2bf(a.x); r[1] = (short)f2bf(a.y);
    r[2] = (short)f2bf(a.z); r[3] = (short)f2bf(a.w);
    r[4] = (short)f2bf(b.x); r[5] = (short)f2bf(b.y);
    r[6] = (short)f2bf(b.z); r[7] = (short)f2bf(b.w);
    return r;
}

// Single dispatch, no grid sync. Block (col-tile, row-window) owns out rows
// m0..m0+15 x cols j0..j0+63. Occurrence structure via per-row ballot masks
// (R7-verified); cross-window predecessor rows ("extras") recomputed locally
// through the same MFMA path (R10-verified math). The 1/n factor is applied
// at the end (n = final walk count), so no separate count scan exists.
__global__ __launch_bounds__(256) void fused_one(
    const float* __restrict__ df, const int* __restrict__ gt,
    const float* __restrict__ fc, float* __restrict__ out)
{
    __shared__ int                s_gt[BB];
    __shared__ unsigned long long s_mask[WROWS][8];
    __shared__ short              s_slot[BB];
    __shared__ short              s_xrow[EMAX];
    __shared__ int                s_E;
    __shared__ unsigned short     Bh[WCOLS][NDF + 8];
    __shared__ float              Gown[WROWS][WCOLS + 2];
    __shared__ float              Gx[EMAX][WCOLS + 2];
    __shared__ float              s_v[WROWS];
    __shared__ float              s_vx[EMAX];
    __shared__ float              s_red[WROWS][16];

    int tid = threadIdx.x;
    int j0 = blockIdx.x * WCOLS;
    int m0 = blockIdx.y * WROWS;

    s_gt[tid]        = gt[tid];
    s_gt[tid + 256]  = gt[tid + 256];
    s_slot[tid]      = -1;
    s_slot[tid + 256] = -1;
    if (tid == 0) s_E = 0;
    __syncthreads();                               // B0

    int lane = tid & 63, w = tid >> 6;
    // ballots: occurrence masks for the 16 window classes (uniform loop)
    int g0 = s_gt[tid], g1 = s_gt[tid + 256];
#pragma unroll
    for (int r = 0; r < WROWS; ++r) {
        int cls = s_gt[m0 + r];
        unsigned long long b0 = __ballot(g0 == cls);
        unsigned long long b1 = __ballot(g1 == cls);
        if (lane == 0) { s_mask[r][w] = b0; s_mask[r][w + 4] = b1; }
    }
    // stage fc col-tile -> bf16 LDS (OOB cols clamp to row 999; never stored)
    {
        int row = tid >> 2, kb = (tid & 3) * 64;
        int fr = j0 + row; if (fr > NCLS - 1) fr = NCLS - 1;
        const float* fp = fc + (size_t)fr * NDF + kb;
#pragma unroll
        for (int u = 0; u < 64; u += 8)
            *(short8*)&Bh[row][kb + u] =
                cvt8(*(const float4*)(fp + u), *(const float4*)(fp + u + 4));
    }
    __syncthreads();                               // B1: masks + Bh ready

    // extras gather: one thread per window row; only first-in-window class
    // rows walk their mask (distinct classes -> disjoint masks -> race-free).
    if (tid < WROWS) {
        int cls = s_gt[m0 + tid];
        bool first = true;
        for (int r2 = 0; r2 < tid; ++r2)
            if (s_gt[m0 + r2] == cls) { first = false; break; }
        if (first && m0 > 0) {
            for (int wi = 0; wi < 8; ++wi) {
                int base = wi * 64;
                if (base >= m0) break;
                unsigned long long mk = s_mask[tid][wi];
                while (mk) {
                    int b = __builtin_ctzll(mk); mk &= mk - 1ULL;
                    int s = base + b;
                    if (s >= m0) break;
                    int p = atomicAdd(&s_E, 1);
                    if (p < EMAX) { s_slot[s] = (short)p; s_xrow[p] = (short)s; }
                    else          { s_slot[s] = (short)(-2); }
                }
            }
        }
    }

    // own-tile MFMA: 16 rows x 64 cols, wave w -> cols w*16 (layout m89-verified)
    int lr = lane & 15, lk8 = (lane >> 4) * 8, cf = w * 16;
    {
        floatx4 acc = {0.f, 0.f, 0.f, 0.f};
        const float* ap = df + (size_t)(m0 + lr) * NDF + lk8;
#pragma unroll
        for (int ks = 0; ks < 8; ++ks) {
            int kb = ks * 32;
            short8 bfrag = *(short8*)&Bh[cf + lr][kb + lk8];
            short8 a0 = cvt8(*(const float4*)(ap + kb), *(const float4*)(ap + kb + 4));
            acc = __builtin_amdgcn_mfma_f32_16x16x32_bf16(a0, bfrag, acc, 0, 0, 0);
        }
        int rb = (lane >> 4) * 4;
#pragma unroll
        for (int g = 0; g < 4; ++g) Gown[rb + g][cf + lr] = acc[g];
    }
    // own v partials: 16 rows x 16 threads, v[i] = df[i].fc[gt[i]]
    {
        int rr = tid >> 4, l = tid & 15;
        int irow = m0 + rr, cls = s_gt[irow];
        const float* dp = df + (size_t)irow * NDF + l * 16;
        const float* fp = fc + (size_t)cls * NDF + l * 16;
        float a = 0.f;
#pragma unroll
        for (int u = 0; u < 16; u += 4) {
            float4 x = *(const float4*)(dp + u), y = *(const float4*)(fp + u);
            a += x.x * y.x + x.y * y.y + x.z * y.z + x.w * y.w;
        }
        s_red[rr][l] = a;
    }
    __syncthreads();                               // B2: gather, Gown, v-partials

    int E = s_E; if (E > EMAX) E = EMAX;
    if (tid < WROWS) {
        float v = 0.f;
#pragma unroll
        for (int u = 0; u < 16; ++u) v += s_red[tid][u];
        s_v[tid] = v;
    }

    // extras MFMA chunks (disjoint Gx rows -> no inner barriers)
    int NCH = (E + 15) >> 4;
    for (int ch = 0; ch < NCH; ++ch) {
        int zi = ch * 16 + lr;
        int srow = (zi < E) ? (int)s_xrow[zi] : 0;
        floatx4 acc = {0.f, 0.f, 0.f, 0.f};
        const float* ep = df + (size_t)srow * NDF + lk8;
#pragma unroll
        for (int ks = 0; ks < 8; ++ks) {
            int kb = ks * 32;
            short8 bfrag = *(short8*)&Bh[cf + lr][kb + lk8];
            short8 a0 = cvt8(*(const float4*)(ep + kb), *(const float4*)(ep + kb + 4));
            acc = __builtin_amdgcn_mfma_f32_16x16x32_bf16(a0, bfrag, acc, 0, 0, 0);
        }
        int rb = (lane >> 4) * 4;
#pragma unroll
        for (int g = 0; g < 4; ++g) Gx[ch * 16 + rb + g][cf + lr] = acc[g];
    }
    // extras v (s_red reuse guarded by barriers; NCH uniform)
    for (int ch = 0; ch < NCH; ++ch) {
        __syncthreads();
        int rr = tid >> 4, l = tid & 15;
        int zi = ch * 16 + rr;
        int srow = (zi < E) ? (int)s_xrow[zi] : 0;
        int cls = s_gt[srow];
        const float* dp = df + (size_t)srow * NDF + l * 16;
        const float* fp = fc + (size_t)cls * NDF + l * 16;
        float a = 0.f;
#pragma unroll
        for (int u = 0; u < 16; u += 4) {
            float4 x = *(const float4*)(dp + u), y = *(const float4*)(fp + u);
            a += x.x * y.x + x.y * y.y + x.z * y.z + x.w * y.w;
        }
        s_red[rr][l] = a;
        __syncthreads();
        if (tid < 16 && ch * 16 + tid < E) {
            float v = 0.f;
#pragma unroll
            for (int u = 0; u < 16; ++u) v += s_red[tid][u];
            s_vx[ch * 16 + tid] = v;
        }
    }
    __syncthreads();                               // Bf: everything ready

    // walk: thread (r, c) -> row m0+r, cols j0+c*4..+3; visits mask set bits
    // ascending; mcnt at the end == n (so 1/n applies as a postfactor).
    int r = tid >> 4, c = tid & 15;
    int i_row = m0 + r;
    int jc = j0 + c * 4;
    int mcnt = 0;
    float St = 0.f;
    float S0 = 0.f, S1 = 0.f, S2 = 0.f, S3 = 0.f;
    float q0 = 0.f, q1 = 0.f, q2 = 0.f, q3 = 0.f;
    for (int wi = 0; wi < 8; ++wi) {
        int base = wi * 64;
        if (base > i_row) break;
        unsigned long long mk = s_mask[r][wi];
        while (mk) {
            int b = __builtin_ctzll(mk); mk &= mk - 1ULL;
            int s = base + b;
            if (s > i_row) break;
            float vz, G0, G1, G2, G3;
            if (s >= m0) {
                int rr = s - m0;
                vz = s_v[rr];
                G0 = Gown[rr][c * 4 + 0]; G1 = Gown[rr][c * 4 + 1];
                G2 = Gown[rr][c * 4 + 2]; G3 = Gown[rr][c * 4 + 3];
            } else {
                int slot = (int)s_slot[s];
                if (slot >= 0) {
                    vz = s_vx[slot];
                    G0 = Gx[slot][c * 4 + 0]; G1 = Gx[slot][c * 4 + 1];
                    G2 = Gx[slot][c * 4 + 2]; G3 = Gx[slot][c * 4 + 3];
                } else {
                    // overflow fallback (E > EMAX; never for this input)
                    const float* dp = df + (size_t)s * NDF;
                    const float* fv = fc + (size_t)s_gt[s] * NDF;
                    int p0 = jc     < NCLS ? jc     : NCLS - 1;
                    int p1 = jc + 1 < NCLS ? jc + 1 : NCLS - 1;
                    int p2 = jc + 2 < NCLS ? jc + 2 : NCLS - 1;
                    int p3 = jc + 3 < NCLS ? jc + 3 : NCLS - 1;
                    vz = 0.f; G0 = G1 = G2 = G3 = 0.f;
                    for (int k = 0; k < NDF; ++k) {
                        float d = dp[k];
                        vz += d * fv[k];
                        G0 += d * fc[(size_t)p0 * NDF + k];
                        G1 += d * fc[(size_t)p1 * NDF + k];
                        G2 += d * fc[(size_t)p2 * NDF + k];
                        G3 += d * fc[(size_t)p3 * NDF + k];
                    }
                }
            }
            ++mcnt;
            St += vz;
            float inv_m = 1.f / (float)mcnt;
            S0 += G0; S1 += G1; S2 += G2; S3 += G3;
            if (mcnt >= 2) {
                float ht = vz - St * inv_m;
                float coef = (float)(mcnt - 1) * inv_m;
                float h0 = (G0 - S0 * inv_m) - ht;
                float h1 = (G1 - S1 * inv_m) - ht;
                float h2 = (G2 - S2 * inv_m) - ht;
                float h3 = (G3 - S3 * inv_m) - ht;
                q0 += coef * h0 * h0;
                q1 += coef * h1 * h1;
                q2 += coef * h2 * h2;
                q3 += coef * h3 * h3;
            }
        }
    }
    if (jc < NCLS) {                               // NCLS%4==0 -> exact guard
        float invn = 1.f / (float)mcnt;
        float sc = 0.05f * invn;                   // 0.5*ALP / n
        float vi = s_v[r];
        *(float4*)&out[(size_t)i_row * NCLS + jc] = make_float4(
            (Gown[r][c * 4 + 0] - vi) + sc * q0,
            (Gown[r][c * 4 + 1] - vi) + sc * q1,
            (Gown[r][c * 4 + 2] - vi) + sc * q2,
            (Gown[r][c * 4 + 3] - vi) + sc * q3);
    }
}

extern "C" void kernel_launch(void* const* d_in, const int* in_sizes, int n_in,
                              void* d_out, int out_size, void* d_ws, size_t ws_size,
                              hipStream_t stream) {
    const float* df = (const float*)d_in[0];
    const int*   gt = (const int*)d_in[1];
    const float* fc = (const float*)d_in[2];
    float* out = (float*)d_out;
    (void)d_ws; (void)ws_size;

    fused_one<<<dim3(16, 32), 256, 0, stream>>>(df, gt, fc, out);
}